// Round 11
// baseline (519.159 us; speedup 1.0000x reference)
//
#include <hip/hip_runtime.h>
#include <hip/hip_bf16.h>

typedef __hip_bfloat16 bf16;
typedef __attribute__((ext_vector_type(8))) __bf16 bf16x8;
typedef __attribute__((ext_vector_type(4))) float f32x4;

__device__ __forceinline__ void gl16(const void* g, void* l) {
  __builtin_amdgcn_global_load_lds((__attribute__((address_space(1))) void*)g,
                                   (__attribute__((address_space(3))) void*)l, 16, 0, 0);
}
__device__ __forceinline__ bf16 f2b(float f) { return __float2bfloat16(f); }

// T2 swizzle for [rows][64 bf16] tiles (128-B rows): XOR byte-col bits 4-6 with row&7.
// (used by flash_fwd / avg_attn LDS staging; conv_qkv is now LDS-free)
__device__ __forceinline__ int swz(int row, int bytecol) {
  return bytecol ^ ((row & 7) << 4);
}

// ---------------- prep: query (L,B,E) fp32 -> Xb[b][l][i] bf16 ----------------
__global__ void __launch_bounds__(256) prep_x(const float* __restrict__ q, bf16* __restrict__ Xb) {
  int row = blockIdx.x;            // b*512 + l
  int b = row >> 9, l = row & 511;
  int t = threadIdx.x;
  float2 v = *(const float2*)(q + (size_t)l * 16384 + b * 512 + t * 2);
  __hip_bfloat162 o2; o2.x = f2b(v.x); o2.y = f2b(v.y);
  *(__hip_bfloat162*)(Xb + (size_t)row * 512 + t * 2) = o2;
}

// ---------------- prep: W (1536,512,3) fp32 -> Wb[t][o][i] bf16 ----------------
__global__ void __launch_bounds__(256) prep_w(const float* __restrict__ w, bf16* __restrict__ Wb) {
  int idx = blockIdx.x * 256 + threadIdx.x;       // < 3*1536*512 = 2359296
  int t = idx / 786432;
  int r = idx - t * 786432;
  int o = r >> 9, i = r & 511;
  Wb[idx] = f2b(w[(size_t)o * 1536 + i * 3 + t]);
}

// ---------------- conv1d QKV as MFMA GEMM, direct-from-L2 (no LDS) ----------------
// Out[o][l] = sum_tap sum_i Wb[tap][o][i] * Xb[b][l+tap-1][i]  (+bias)
// 128x128 tile, 4 waves each 64x64. Fragments are contiguous 16B/lane in Wb/Xb,
// so A/B are loaded straight into registers; W/X are L2/L3-resident (4.7+16 MB).
// No barriers, no staging => no vmcnt(0) drain (the round-10 bottleneck).
__global__ void __launch_bounds__(256) conv_qkv(
    const bf16* __restrict__ Wb, const bf16* __restrict__ Xb,
    const float* __restrict__ bias, const char* __restrict__ zp,
    bf16* __restrict__ Qb, bf16* __restrict__ Kb, bf16* __restrict__ Vt) {
  const int tid = threadIdx.x;
  const int l0 = blockIdx.x * 128;
  const int o0 = blockIdx.y * 128;
  const int b  = blockIdx.z;
  const int lane = tid & 63, wid = tid >> 6;
  const int wm = (wid >> 1) * 64, wn = (wid & 1) * 64;
  const int lg = lane >> 4, lr = lane & 15;

  f32x4 acc[4][4] = {};

  for (int tap = 0; tap < 3; ++tap) {
    const bf16* ab[4];
    const bf16* bbp[4];
    #pragma unroll
    for (int i = 0; i < 4; ++i)
      ab[i] = Wb + (size_t)tap * 786432 + (size_t)(o0 + wm + i * 16 + lr) * 512 + lg * 8;
    #pragma unroll
    for (int j = 0; j < 4; ++j) {
      int l = l0 + wn + j * 16 + lr + tap - 1;
      const bf16* p = (l < 0 || l >= 512) ? (const bf16*)zp
                                          : Xb + (size_t)(b * 512 + l) * 512;
      bbp[j] = p + lg * 8;   // zp offsets stay < 4096B (zeroed page)
    }
    #pragma unroll
    for (int k0 = 0; k0 < 512; k0 += 64) {
      #pragma unroll
      for (int kk = 0; kk < 2; ++kk) {
        bf16x8 a[4], bv[4];
        #pragma unroll
        for (int i = 0; i < 4; ++i)
          a[i] = *(const bf16x8*)(ab[i] + k0 + kk * 32);
        #pragma unroll
        for (int j = 0; j < 4; ++j)
          bv[j] = *(const bf16x8*)(bbp[j] + k0 + kk * 32);
        #pragma unroll
        for (int i = 0; i < 4; ++i)
          #pragma unroll
          for (int j = 0; j < 4; ++j)
            acc[i][j] = __builtin_amdgcn_mfma_f32_16x16x32_bf16(a[i], bv[j], acc[i][j], 0, 0, 0);
      }
    }
  }

  const int part = o0 >> 9;   // uniform per block (o-tile 128 | 512)
  #pragma unroll
  for (int i = 0; i < 4; ++i) {
    #pragma unroll
    for (int j = 0; j < 4; ++j) {
      int mbase = o0 + wm + i * 16 + lg * 4;
      int l = l0 + wn + j * 16 + lr;
      #pragma unroll
      for (int r = 0; r < 4; ++r) {
        int o = mbase + r;
        float v = acc[i][j][r] + bias[o];
        int rem = o & 511;
        int h = rem >> 6, d = rem & 63;
        size_t bh = (size_t)(b * 8 + h);
        if (part == 0)      Qb[(bh * 512 + l) * 64 + d] = f2b(v * 0.125f);
        else if (part == 1) Kb[(bh * 512 + l) * 64 + d] = f2b(v);
        else                Vt[(bh * 64 + d) * 512 + l] = f2b(v);
      }
    }
  }
}

// ---------------- flash attention fwd: out0 + (rowmax, 1/denom) ----------------
__global__ void __launch_bounds__(256) flash_fwd(
    const bf16* __restrict__ Qb, const bf16* __restrict__ Kb, const bf16* __restrict__ Vt,
    float* __restrict__ out0, float* __restrict__ m_arr, float* __restrict__ li_arr) {
  __shared__ __align__(16) bf16 Qs[64 * 64];
  __shared__ __align__(16) bf16 Ks[64 * 64];
  __shared__ __align__(16) bf16 Vs[64 * 64];
  __shared__ __align__(16) bf16 Ps[4][16 * 72];   // padded rows (144 B) vs bank conflicts
  const int tid = threadIdx.x;
  const int t0 = blockIdx.x * 64;
  const int bh = blockIdx.y;
  const int b = bh >> 3, h = bh & 7;
  const int lane = tid & 63, w = tid >> 6;
  const int lg = lane >> 4, lr = lane & 15;
  const int rsw = (lr & 7) << 4;

  #pragma unroll
  for (int it = 0; it < 2; ++it) {
    int ofs = tid * 16 + it * 4096;
    int row = ofs >> 7, bc = swz(row, ofs & 127);
    gl16((const char*)(Qb + ((size_t)bh * 512 + t0 + row) * 64) + bc, (char*)Qs + ofs);
  }

  float mreg[4] = {-1e30f, -1e30f, -1e30f, -1e30f};
  float lreg[4] = {0.f, 0.f, 0.f, 0.f};
  f32x4 oacc[4] = {};

  for (int sc = 0; sc < 8; ++sc) {
    __syncthreads();
    #pragma unroll
    for (int it = 0; it < 2; ++it) {
      int ofs = tid * 16 + it * 4096;
      int row = ofs >> 7, bc = swz(row, ofs & 127);
      gl16((const char*)(Kb + ((size_t)bh * 512 + sc * 64 + row) * 64) + bc, (char*)Ks + ofs);
      gl16((const char*)(Vt + ((size_t)bh * 64 + row) * 512 + sc * 64) + bc, (char*)Vs + ofs);
    }
    __syncthreads();

    bf16x8 aq[2];
    #pragma unroll
    for (int kk = 0; kk < 2; ++kk)
      aq[kk] = *(const bf16x8*)((const char*)Qs + (w * 16 + lr) * 128 + ((kk * 64 + lg * 16) ^ rsw));

    f32x4 s4[4] = {};
    #pragma unroll
    for (int j = 0; j < 4; ++j)
      #pragma unroll
      for (int kk = 0; kk < 2; ++kk) {
        bf16x8 bk = *(const bf16x8*)((const char*)Ks + (j * 16 + lr) * 128 + ((kk * 64 + lg * 16) ^ rsw));
        s4[j] = __builtin_amdgcn_mfma_f32_16x16x32_bf16(aq[kk], bk, s4[j], 0, 0, 0);
      }

    float cm[4], mnew[4], alpha[4], rs[4];
    #pragma unroll
    for (int r = 0; r < 4; ++r) {
      cm[r] = fmaxf(fmaxf(s4[0][r], s4[1][r]), fmaxf(s4[2][r], s4[3][r]));
      cm[r] = fmaxf(cm[r], __shfl_xor(cm[r], 1, 64));
      cm[r] = fmaxf(cm[r], __shfl_xor(cm[r], 2, 64));
      cm[r] = fmaxf(cm[r], __shfl_xor(cm[r], 4, 64));
      cm[r] = fmaxf(cm[r], __shfl_xor(cm[r], 8, 64));
      mnew[r] = fmaxf(mreg[r], cm[r]);
      alpha[r] = __expf(mreg[r] - mnew[r]);
      rs[r] = 0.f;
    }
    #pragma unroll
    for (int j = 0; j < 4; ++j)
      #pragma unroll
      for (int r = 0; r < 4; ++r) {
        float p = __expf(s4[j][r] - mnew[r]);
        s4[j][r] = p;
        rs[r] += p;
      }
    #pragma unroll
    for (int r = 0; r < 4; ++r) {
      rs[r] += __shfl_xor(rs[r], 1, 64);
      rs[r] += __shfl_xor(rs[r], 2, 64);
      rs[r] += __shfl_xor(rs[r], 4, 64);
      rs[r] += __shfl_xor(rs[r], 8, 64);
      lreg[r] = lreg[r] * alpha[r] + rs[r];
      mreg[r] = mnew[r];
    }
    #pragma unroll
    for (int j = 0; j < 4; ++j)
      #pragma unroll
      for (int r = 0; r < 4; ++r)
        oacc[j][r] *= alpha[r];

    // P -> per-wave LDS (bf16, padded rows), then read back as A-fragments
    #pragma unroll
    for (int j = 0; j < 4; ++j)
      #pragma unroll
      for (int r = 0; r < 4; ++r)
        Ps[w][(lg * 4 + r) * 72 + j * 16 + lr] = f2b(s4[j][r]);
    asm volatile("s_waitcnt lgkmcnt(0)" ::: "memory");
    __builtin_amdgcn_sched_barrier(0);

    bf16x8 pa[2];
    #pragma unroll
    for (int kk = 0; kk < 2; ++kk)
      pa[kk] = *(const bf16x8*)((const char*)&Ps[w][0] + lr * 144 + kk * 64 + lg * 16);

    #pragma unroll
    for (int j = 0; j < 4; ++j)
      #pragma unroll
      for (int kk = 0; kk < 2; ++kk) {
        bf16x8 bv = *(const bf16x8*)((const char*)Vs + (j * 16 + lr) * 128 + ((kk * 64 + lg * 16) ^ rsw));
        oacc[j] = __builtin_amdgcn_mfma_f32_16x16x32_bf16(pa[kk], bv, oacc[j], 0, 0, 0);
      }
  }

  float il[4];
  #pragma unroll
  for (int r = 0; r < 4; ++r) il[r] = 1.f / lreg[r];

  #pragma unroll
  for (int j = 0; j < 4; ++j)
    #pragma unroll
    for (int r = 0; r < 4; ++r) {
      int t = t0 + w * 16 + lg * 4 + r;
      out0[(size_t)t * 16384 + (size_t)b * 512 + h * 64 + j * 16 + lr] = oacc[j][r] * il[r];
    }
  if (lr == 0) {
    #pragma unroll
    for (int r = 0; r < 4; ++r) {
      int t = t0 + w * 16 + lg * 4 + r;
      m_arr[bh * 512 + t] = mreg[r];
      li_arr[bh * 512 + t] = il[r];
    }
  }
}

// ---------------- avg_weights: recompute P from saved (m, 1/l), sum heads ----------------
__global__ void __launch_bounds__(256) avg_attn(
    const bf16* __restrict__ Qb, const bf16* __restrict__ Kb,
    const float* __restrict__ m_arr, const float* __restrict__ li_arr,
    float* __restrict__ out1) {
  __shared__ __align__(16) bf16 Qs[64 * 64];
  __shared__ __align__(16) bf16 Ks[128 * 64];
  const int tid = threadIdx.x;
  const int s0 = blockIdx.x * 128;
  const int t0 = blockIdx.y * 64;
  const int b  = blockIdx.z;
  const int lane = tid & 63, w = tid >> 6;
  const int lg = lane >> 4, lr = lane & 15;
  const int rsw = (lr & 7) << 4;

  f32x4 avg4[8] = {};

  for (int h = 0; h < 8; ++h) {
    int bh = b * 8 + h;
    __syncthreads();
    #pragma unroll
    for (int it = 0; it < 2; ++it) {
      int ofs = tid * 16 + it * 4096;
      int row = ofs >> 7, bc = swz(row, ofs & 127);
      gl16((const char*)(Qb + ((size_t)bh * 512 + t0 + row) * 64) + bc, (char*)Qs + ofs);
    }
    #pragma unroll
    for (int it = 0; it < 4; ++it) {
      int ofs = tid * 16 + it * 4096;
      int row = ofs >> 7, bc = swz(row, ofs & 127);
      gl16((const char*)(Kb + ((size_t)bh * 512 + s0 + row) * 64) + bc, (char*)Ks + ofs);
    }
    __syncthreads();

    float mv[4], iv[4];
    #pragma unroll
    for (int r = 0; r < 4; ++r) {
      int t = t0 + w * 16 + lg * 4 + r;
      mv[r] = m_arr[bh * 512 + t];
      iv[r] = li_arr[bh * 512 + t];
    }

    bf16x8 aq[2];
    #pragma unroll
    for (int kk = 0; kk < 2; ++kk)
      aq[kk] = *(const bf16x8*)((const char*)Qs + (w * 16 + lr) * 128 + ((kk * 64 + lg * 16) ^ rsw));

    #pragma unroll
    for (int j = 0; j < 8; ++j) {
      f32x4 s4 = {};
      #pragma unroll
      for (int kk = 0; kk < 2; ++kk) {
        bf16x8 bk = *(const bf16x8*)((const char*)Ks + (j * 16 + lr) * 128 + ((kk * 64 + lg * 16) ^ rsw));
        s4 = __builtin_amdgcn_mfma_f32_16x16x32_bf16(aq[kk], bk, s4, 0, 0, 0);
      }
      #pragma unroll
      for (int r = 0; r < 4; ++r)
        avg4[j][r] += __expf(s4[r] - mv[r]) * iv[r];
    }
  }

  #pragma unroll
  for (int j = 0; j < 8; ++j)
    #pragma unroll
    for (int r = 0; r < 4; ++r) {
      int t = t0 + w * 16 + lg * 4 + r;
      out1[((size_t)b * 512 + t) * 512 + s0 + j * 16 + lr] = avg4[j][r] * 0.125f;
    }
}

extern "C" void kernel_launch(void* const* d_in, const int* in_sizes, int n_in,
                              void* d_out, int out_size, void* d_ws, size_t ws_size,
                              hipStream_t stream) {
  const float* query = (const float*)d_in[0];
  const float* wconv = (const float*)d_in[1];
  const float* bias  = (const float*)d_in[2];
  // d_in[3] (attention_weight) and d_in[4] (bpps) are unused by the reference.

  char* ws = (char*)d_ws;
  bf16* Xb  = (bf16*)(ws + 0);                 // 16,777,216 B
  bf16* Wb  = (bf16*)(ws + 16777216);          //  4,718,592 B
  bf16* Qb  = (bf16*)(ws + 21495808);          // 16,777,216 B
  bf16* Kb  = (bf16*)(ws + 38273024);          // 16,777,216 B
  bf16* Vt  = (bf16*)(ws + 55050240);          // 16,777,216 B
  float* m_arr  = (float*)(ws + 71827456);     //    524,288 B
  float* li_arr = (float*)(ws + 72351744);     //    524,288 B
  char* zp = ws + 72876032;                    //      4,096 B (zero page)

  float* out0 = (float*)d_out;                 // (512,32,512)
  float* out1 = out0 + 8388608;                // (32,512,512)

  hipMemsetAsync(zp, 0, 4096, stream);
  prep_x<<<16384, 256, 0, stream>>>(query, Xb);
  prep_w<<<9216, 256, 0, stream>>>(wconv, Wb);
  conv_qkv<<<dim3(4, 12, 32), 256, 0, stream>>>(Wb, Xb, bias, zp, Qb, Kb, Vt);
  flash_fwd<<<dim3(8, 256), 256, 0, stream>>>(Qb, Kb, Vt, out0, m_arr, li_arr);
  avg_attn<<<dim3(4, 8, 32), 256, 0, stream>>>(Qb, Kb, m_arr, li_arr, out1);
}

// Round 13
// 363.425 us; speedup vs baseline: 1.4285x; 1.4285x over previous
//
#include <hip/hip_runtime.h>
#include <hip/hip_bf16.h>

typedef __hip_bfloat16 bf16;
typedef __attribute__((ext_vector_type(8))) __bf16 bf16x8;
typedef __attribute__((ext_vector_type(4))) float f32x4;

__device__ __forceinline__ void gl16(const void* g, void* l) {
  __builtin_amdgcn_global_load_lds((__attribute__((address_space(1))) void*)g,
                                   (__attribute__((address_space(3))) void*)l, 16, 0, 0);
}
__device__ __forceinline__ bf16 f2b(float f) { return __float2bfloat16(f); }

// T2 swizzle for [rows][64 bf16] tiles (128-B rows): XOR byte-col bits 4-6 with row&7.
// Staging pre-swizzles the GLOBAL source col (gl16 writes LDS linearly); reads apply
// the same XOR. Involution => correct. Verified r10: bank conflicts 2.83e7 -> 0.
__device__ __forceinline__ int swz(int row, int bytecol) {
  return bytecol ^ ((row & 7) << 4);
}

// ---------------- prep: query (L,B,E) fp32 -> Xp[b][l+1][i] bf16 (padded halo rows) ----
__global__ void __launch_bounds__(256) prep_x(const float* __restrict__ q, bf16* __restrict__ Xp) {
  int row = blockIdx.x;            // b*512 + l
  int b = row >> 9, l = row & 511;
  int t = threadIdx.x;
  float2 v = *(const float2*)(q + (size_t)l * 16384 + b * 512 + t * 2);
  __hip_bfloat162 o2; o2.x = f2b(v.x); o2.y = f2b(v.y);
  *(__hip_bfloat162*)(Xp + ((size_t)(b * 514 + l + 1)) * 512 + t * 2) = o2;
}

// ---------------- prep: W (1536,512,3) fp32 -> Wb[t][o][i] bf16 ----------------
__global__ void __launch_bounds__(256) prep_w(const float* __restrict__ w, bf16* __restrict__ Wb) {
  int idx = blockIdx.x * 256 + threadIdx.x;       // < 3*1536*512 = 2359296
  int t = idx / 786432;
  int r = idx - t * 786432;
  int o = r >> 9, i = r & 511;
  Wb[idx] = f2b(w[(size_t)o * 1536 + i * 3 + t]);
}

// ---------------- conv1d QKV as MFMA GEMM, 2-phase double-buffered LDS ----------------
// Out[o][l] = sum_tap sum_i Wb[tap][o][i] * Xp[b][l+tap][i]  (+bias)  [Xp row l+1 = X row l]
// 128x128 tile, BK=64, 4 waves each 64x64. Stage(t+1) overlaps compute(t); ONE barrier/step.
__global__ void __launch_bounds__(256) conv_qkv(
    const bf16* __restrict__ Wb, const bf16* __restrict__ Xp,
    const float* __restrict__ bias,
    bf16* __restrict__ Qb, bf16* __restrict__ Kb, bf16* __restrict__ Vt) {
  __shared__ __align__(16) bf16 As[2][128 * 64];
  __shared__ __align__(16) bf16 Bs[2][128 * 64];
  const int tid = threadIdx.x;
  const int l0 = blockIdx.x * 128;
  const int o0 = blockIdx.y * 128;
  const int b  = blockIdx.z;
  const int lane = tid & 63, wid = tid >> 6;
  const int wm = (wid >> 1) * 64, wn = (wid & 1) * 64;
  const int lg = lane >> 4, lr = lane & 15;
  const int rsw = (lr & 7) << 4;   // read-side XOR (row&7 == lr&7 for all frag rows)

  f32x4 acc[4][4] = {};

  auto STAGE = [&](int step, int buf) {
    const int tap = step >> 3;
    const int k0 = (step & 7) * 64;
    const char* wbase = (const char*)Wb + ((size_t)tap * 786432 + (size_t)o0 * 512 + k0) * 2;
    const char* xbase = (const char*)Xp + (((size_t)(b * 514 + l0 + tap)) * 512 + k0) * 2;
    #pragma unroll
    for (int it = 0; it < 4; ++it) {       // A tile [128][64] = 16KB
      int ofs = tid * 16 + it * 4096;
      int row = ofs >> 7, bc = swz(row, ofs & 127);
      gl16(wbase + (size_t)row * 1024 + bc, (char*)&As[buf][0] + ofs);
    }
    #pragma unroll
    for (int it = 0; it < 4; ++it) {       // B tile [128][64], branchless (padded halo)
      int ofs = tid * 16 + it * 4096;
      int row = ofs >> 7, bc = swz(row, ofs & 127);
      gl16(xbase + (size_t)row * 1024 + bc, (char*)&Bs[buf][0] + ofs);
    }
  };

  STAGE(0, 0);
  int cur = 0;
  for (int step = 0; step < 24; ++step) {
    __syncthreads();                       // drains vmcnt(0): buf[cur] ready; prev reads done
    if (step < 23) STAGE(step + 1, cur ^ 1);   // in flight across the MFMA block below
    #pragma unroll
    for (int kk = 0; kk < 2; ++kk) {
      const int rcol = (kk * 64 + lg * 16) ^ rsw;
      bf16x8 a[4], bb[4];
      #pragma unroll
      for (int i = 0; i < 4; ++i)
        a[i] = *(const bf16x8*)((const char*)&As[cur][0] + (wm + i * 16 + lr) * 128 + rcol);
      #pragma unroll
      for (int j = 0; j < 4; ++j)
        bb[j] = *(const bf16x8*)((const char*)&Bs[cur][0] + (wn + j * 16 + lr) * 128 + rcol);
      #pragma unroll
      for (int i = 0; i < 4; ++i)
        #pragma unroll
        for (int j = 0; j < 4; ++j)
          acc[i][j] = __builtin_amdgcn_mfma_f32_16x16x32_bf16(a[i], bb[j], acc[i][j], 0, 0, 0);
    }
    cur ^= 1;
  }

  const int part = o0 >> 9;   // uniform per block (o-tile 128 | 512)
  #pragma unroll
  for (int i = 0; i < 4; ++i) {
    #pragma unroll
    for (int j = 0; j < 4; ++j) {
      int mbase = o0 + wm + i * 16 + lg * 4;
      int l = l0 + wn + j * 16 + lr;
      #pragma unroll
      for (int r = 0; r < 4; ++r) {
        int o = mbase + r;
        float v = acc[i][j][r] + bias[o];
        int rem = o & 511;
        int h = rem >> 6, d = rem & 63;
        size_t bh = (size_t)(b * 8 + h);
        if (part == 0)      Qb[(bh * 512 + l) * 64 + d] = f2b(v * 0.125f);
        else if (part == 1) Kb[(bh * 512 + l) * 64 + d] = f2b(v);
        else                Vt[(bh * 64 + d) * 512 + l] = f2b(v);
      }
    }
  }
}

// ---------------- flash attention fwd: out0 + (rowmax, 1/denom) ----------------
__global__ void __launch_bounds__(256) flash_fwd(
    const bf16* __restrict__ Qb, const bf16* __restrict__ Kb, const bf16* __restrict__ Vt,
    float* __restrict__ out0, float* __restrict__ m_arr, float* __restrict__ li_arr) {
  __shared__ __align__(16) bf16 Qs[64 * 64];
  __shared__ __align__(16) bf16 Ks[64 * 64];
  __shared__ __align__(16) bf16 Vs[64 * 64];
  __shared__ __align__(16) bf16 Ps[4][16 * 72];   // padded rows (144 B) vs bank conflicts
  const int tid = threadIdx.x;
  const int t0 = blockIdx.x * 64;
  const int bh = blockIdx.y;
  const int b = bh >> 3, h = bh & 7;
  const int lane = tid & 63, w = tid >> 6;
  const int lg = lane >> 4, lr = lane & 15;
  const int rsw = (lr & 7) << 4;

  #pragma unroll
  for (int it = 0; it < 2; ++it) {
    int ofs = tid * 16 + it * 4096;
    int row = ofs >> 7, bc = swz(row, ofs & 127);
    gl16((const char*)(Qb + ((size_t)bh * 512 + t0 + row) * 64) + bc, (char*)Qs + ofs);
  }

  float mreg[4] = {-1e30f, -1e30f, -1e30f, -1e30f};
  float lreg[4] = {0.f, 0.f, 0.f, 0.f};
  f32x4 oacc[4] = {};

  for (int sc = 0; sc < 8; ++sc) {
    __syncthreads();
    #pragma unroll
    for (int it = 0; it < 2; ++it) {
      int ofs = tid * 16 + it * 4096;
      int row = ofs >> 7, bc = swz(row, ofs & 127);
      gl16((const char*)(Kb + ((size_t)bh * 512 + sc * 64 + row) * 64) + bc, (char*)Ks + ofs);
      gl16((const char*)(Vt + ((size_t)bh * 64 + row) * 512 + sc * 64) + bc, (char*)Vs + ofs);
    }
    __syncthreads();

    bf16x8 aq[2];
    #pragma unroll
    for (int kk = 0; kk < 2; ++kk)
      aq[kk] = *(const bf16x8*)((const char*)Qs + (w * 16 + lr) * 128 + ((kk * 64 + lg * 16) ^ rsw));

    f32x4 s4[4] = {};
    #pragma unroll
    for (int j = 0; j < 4; ++j)
      #pragma unroll
      for (int kk = 0; kk < 2; ++kk) {
        bf16x8 bk = *(const bf16x8*)((const char*)Ks + (j * 16 + lr) * 128 + ((kk * 64 + lg * 16) ^ rsw));
        s4[j] = __builtin_amdgcn_mfma_f32_16x16x32_bf16(aq[kk], bk, s4[j], 0, 0, 0);
      }

    float cm[4], mnew[4], alpha[4], rs[4];
    #pragma unroll
    for (int r = 0; r < 4; ++r) {
      cm[r] = fmaxf(fmaxf(s4[0][r], s4[1][r]), fmaxf(s4[2][r], s4[3][r]));
      cm[r] = fmaxf(cm[r], __shfl_xor(cm[r], 1, 64));
      cm[r] = fmaxf(cm[r], __shfl_xor(cm[r], 2, 64));
      cm[r] = fmaxf(cm[r], __shfl_xor(cm[r], 4, 64));
      cm[r] = fmaxf(cm[r], __shfl_xor(cm[r], 8, 64));
      mnew[r] = fmaxf(mreg[r], cm[r]);
      alpha[r] = __expf(mreg[r] - mnew[r]);
      rs[r] = 0.f;
    }
    #pragma unroll
    for (int j = 0; j < 4; ++j)
      #pragma unroll
      for (int r = 0; r < 4; ++r) {
        float p = __expf(s4[j][r] - mnew[r]);
        s4[j][r] = p;
        rs[r] += p;
      }
    #pragma unroll
    for (int r = 0; r < 4; ++r) {
      rs[r] += __shfl_xor(rs[r], 1, 64);
      rs[r] += __shfl_xor(rs[r], 2, 64);
      rs[r] += __shfl_xor(rs[r], 4, 64);
      rs[r] += __shfl_xor(rs[r], 8, 64);
      lreg[r] = lreg[r] * alpha[r] + rs[r];
      mreg[r] = mnew[r];
    }
    #pragma unroll
    for (int j = 0; j < 4; ++j)
      #pragma unroll
      for (int r = 0; r < 4; ++r)
        oacc[j][r] *= alpha[r];

    // P -> per-wave LDS (bf16, padded rows), then read back as A-fragments
    #pragma unroll
    for (int j = 0; j < 4; ++j)
      #pragma unroll
      for (int r = 0; r < 4; ++r)
        Ps[w][(lg * 4 + r) * 72 + j * 16 + lr] = f2b(s4[j][r]);
    asm volatile("s_waitcnt lgkmcnt(0)" ::: "memory");
    __builtin_amdgcn_sched_barrier(0);

    bf16x8 pa[2];
    #pragma unroll
    for (int kk = 0; kk < 2; ++kk)
      pa[kk] = *(const bf16x8*)((const char*)&Ps[w][0] + lr * 144 + kk * 64 + lg * 16);

    #pragma unroll
    for (int j = 0; j < 4; ++j)
      #pragma unroll
      for (int kk = 0; kk < 2; ++kk) {
        bf16x8 bv = *(const bf16x8*)((const char*)Vs + (j * 16 + lr) * 128 + ((kk * 64 + lg * 16) ^ rsw));
        oacc[j] = __builtin_amdgcn_mfma_f32_16x16x32_bf16(pa[kk], bv, oacc[j], 0, 0, 0);
      }
  }

  float il[4];
  #pragma unroll
  for (int r = 0; r < 4; ++r) il[r] = 1.f / lreg[r];

  #pragma unroll
  for (int j = 0; j < 4; ++j)
    #pragma unroll
    for (int r = 0; r < 4; ++r) {
      int t = t0 + w * 16 + lg * 4 + r;
      out0[(size_t)t * 16384 + (size_t)b * 512 + h * 64 + j * 16 + lr] = oacc[j][r] * il[r];
    }
  if (lr == 0) {
    #pragma unroll
    for (int r = 0; r < 4; ++r) {
      int t = t0 + w * 16 + lg * 4 + r;
      m_arr[bh * 512 + t] = mreg[r];
      li_arr[bh * 512 + t] = il[r];
    }
  }
}

// ---------------- avg_weights: recompute P from saved (m, 1/l), sum heads ----------------
__global__ void __launch_bounds__(256) avg_attn(
    const bf16* __restrict__ Qb, const bf16* __restrict__ Kb,
    const float* __restrict__ m_arr, const float* __restrict__ li_arr,
    float* __restrict__ out1) {
  __shared__ __align__(16) bf16 Qs[64 * 64];
  __shared__ __align__(16) bf16 Ks[128 * 64];
  const int tid = threadIdx.x;
  const int s0 = blockIdx.x * 128;
  const int t0 = blockIdx.y * 64;
  const int b  = blockIdx.z;
  const int lane = tid & 63, w = tid >> 6;
  const int lg = lane >> 4, lr = lane & 15;
  const int rsw = (lr & 7) << 4;

  f32x4 avg4[8] = {};

  for (int h = 0; h < 8; ++h) {
    int bh = b * 8 + h;
    __syncthreads();
    #pragma unroll
    for (int it = 0; it < 2; ++it) {
      int ofs = tid * 16 + it * 4096;
      int row = ofs >> 7, bc = swz(row, ofs & 127);
      gl16((const char*)(Qb + ((size_t)bh * 512 + t0 + row) * 64) + bc, (char*)Qs + ofs);
    }
    #pragma unroll
    for (int it = 0; it < 4; ++it) {
      int ofs = tid * 16 + it * 4096;
      int row = ofs >> 7, bc = swz(row, ofs & 127);
      gl16((const char*)(Kb + ((size_t)bh * 512 + s0 + row) * 64) + bc, (char*)Ks + ofs);
    }
    __syncthreads();

    float mv[4], iv[4];
    #pragma unroll
    for (int r = 0; r < 4; ++r) {
      int t = t0 + w * 16 + lg * 4 + r;
      mv[r] = m_arr[bh * 512 + t];
      iv[r] = li_arr[bh * 512 + t];
    }

    bf16x8 aq[2];
    #pragma unroll
    for (int kk = 0; kk < 2; ++kk)
      aq[kk] = *(const bf16x8*)((const char*)Qs + (w * 16 + lr) * 128 + ((kk * 64 + lg * 16) ^ rsw));

    #pragma unroll
    for (int j = 0; j < 8; ++j) {
      f32x4 s4 = {};
      #pragma unroll
      for (int kk = 0; kk < 2; ++kk) {
        bf16x8 bk = *(const bf16x8*)((const char*)Ks + (j * 16 + lr) * 128 + ((kk * 64 + lg * 16) ^ rsw));
        s4 = __builtin_amdgcn_mfma_f32_16x16x32_bf16(aq[kk], bk, s4, 0, 0, 0);
      }
      #pragma unroll
      for (int r = 0; r < 4; ++r)
        avg4[j][r] += __expf(s4[r] - mv[r]) * iv[r];
    }
  }

  #pragma unroll
  for (int j = 0; j < 8; ++j)
    #pragma unroll
    for (int r = 0; r < 4; ++r) {
      int t = t0 + w * 16 + lg * 4 + r;
      out1[((size_t)b * 512 + t) * 512 + s0 + j * 16 + lr] = avg4[j][r] * 0.125f;
    }
}

extern "C" void kernel_launch(void* const* d_in, const int* in_sizes, int n_in,
                              void* d_out, int out_size, void* d_ws, size_t ws_size,
                              hipStream_t stream) {
  const float* query = (const float*)d_in[0];
  const float* wconv = (const float*)d_in[1];
  const float* bias  = (const float*)d_in[2];
  // d_in[3] (attention_weight) and d_in[4] (bpps) are unused by the reference.

  char* ws = (char*)d_ws;
  bf16* Xp  = (bf16*)(ws + 0);                 // 16,842,752 B  (32 x 514 x 512, halo rows)
  bf16* Wb  = (bf16*)(ws + 16842752);          //  4,718,592 B
  bf16* Qb  = (bf16*)(ws + 21561344);          // 16,777,216 B
  bf16* Kb  = (bf16*)(ws + 38338560);          // 16,777,216 B
  bf16* Vt  = (bf16*)(ws + 55115776);          // 16,777,216 B
  float* m_arr  = (float*)(ws + 71892992);     //    524,288 B
  float* li_arr = (float*)(ws + 72417280);     //    524,288 B

  float* out0 = (float*)d_out;                 // (512,32,512)
  float* out1 = out0 + 8388608;                // (32,512,512)

  hipMemsetAsync(Xp, 0, 16842752, stream);     // zero halo rows (interior overwritten by prep_x)
  prep_x<<<16384, 256, 0, stream>>>(query, Xp);
  prep_w<<<9216, 256, 0, stream>>>(wconv, Wb);
  conv_qkv<<<dim3(4, 12, 32), 256, 0, stream>>>(Wb, Xp, bias, Qb, Kb, Vt);
  flash_fwd<<<dim3(8, 256), 256, 0, stream>>>(Qb, Kb, Vt, out0, m_arr, li_arr);
  avg_attn<<<dim3(4, 8, 32), 256, 0, stream>>>(Qb, Kb, m_arr, li_arr, out1);
}

// Round 14
// 351.814 us; speedup vs baseline: 1.4757x; 1.0330x over previous
//
#include <hip/hip_runtime.h>
#include <hip/hip_bf16.h>

typedef __hip_bfloat16 bf16;
typedef __attribute__((ext_vector_type(8))) __bf16 bf16x8;
typedef __attribute__((ext_vector_type(4))) float f32x4;

__device__ __forceinline__ void gl16(const void* g, void* l) {
  __builtin_amdgcn_global_load_lds((__attribute__((address_space(1))) void*)g,
                                   (__attribute__((address_space(3))) void*)l, 16, 0, 0);
}
__device__ __forceinline__ bf16 f2b(float f) { return __float2bfloat16(f); }

// T2 swizzle for [rows][64 bf16] tiles (128-B rows): XOR byte-col bits 4-6 with row&7.
// Staging pre-swizzles the GLOBAL source col (gl16 writes LDS linearly); reads apply
// the same XOR. Involution => correct. Verified r10: bank conflicts 2.83e7 -> 0.
__device__ __forceinline__ int swz(int row, int bytecol) {
  return bytecol ^ ((row & 7) << 4);
}

// ---------------- prep: query (L,B,E) fp32 -> Xp[b][l+1][i] bf16 (padded halo rows) ----
__global__ void __launch_bounds__(256) prep_x(const float* __restrict__ q, bf16* __restrict__ Xp) {
  int row = blockIdx.x;            // b*512 + l
  int b = row >> 9, l = row & 511;
  int t = threadIdx.x;
  float2 v = *(const float2*)(q + (size_t)l * 16384 + b * 512 + t * 2);
  __hip_bfloat162 o2; o2.x = f2b(v.x); o2.y = f2b(v.y);
  *(__hip_bfloat162*)(Xp + ((size_t)(b * 514 + l + 1)) * 512 + t * 2) = o2;
}

// ---------------- prep: W (1536,512,3) fp32 -> Wb[t][o][i] bf16 ----------------
__global__ void __launch_bounds__(256) prep_w(const float* __restrict__ w, bf16* __restrict__ Wb) {
  int idx = blockIdx.x * 256 + threadIdx.x;       // < 3*1536*512 = 2359296
  int t = idx / 786432;
  int r = idx - t * 786432;
  int o = r >> 9, i = r & 511;
  Wb[idx] = f2b(w[(size_t)o * 1536 + i * 3 + t]);
}

// ---------------- conv1d QKV as MFMA GEMM, tap-merged 8-phase 2-stage ----------------
// Out[o][l] = sum_tap sum_i Wb[tap][o][i] * Xp[b][l+tap][i]  (+bias)  [Xp row l+1 = X row l]
// 8 k0-phases; per phase: stage {3 A-tap-tiles + 130-row B-tile} for phase+1, compute
// 96 MFMAs/wave on current buffers. B tap-shift = row offset in the SAME tile (X staged
// once, not 3x); barriers 24 -> 8. LDS 130KB -> 1 block/CU; grid 1536 = 6.0 clean rounds.
__global__ void __launch_bounds__(256) conv_qkv(
    const bf16* __restrict__ Wb, const bf16* __restrict__ Xp,
    const float* __restrict__ bias,
    bf16* __restrict__ Qb, bf16* __restrict__ Kb, bf16* __restrict__ Vt) {
  __shared__ __align__(16) bf16 As[2][3][128 * 64];   // 96 KB
  __shared__ __align__(16) bf16 Bs[2][136 * 64];      // 34 KB (rows 0..129 used)
  const int tid = threadIdx.x;
  const int l0 = blockIdx.x * 128;
  const int o0 = blockIdx.y * 128;
  const int b  = blockIdx.z;
  const int lane = tid & 63, wid = tid >> 6;
  const int wm = (wid >> 1) * 64, wn = (wid & 1) * 64;
  const int lg = lane >> 4, lr = lane & 15;

  f32x4 acc[4][4] = {};

  auto STAGE = [&](int k0, int buf) {
    const char* wb0 = (const char*)Wb + ((size_t)o0 * 512 + k0) * 2;
    const char* xb0 = (const char*)Xp + (((size_t)(b * 514 + l0)) * 512 + k0) * 2;
    #pragma unroll
    for (int tap = 0; tap < 3; ++tap) {
      const char* wt = wb0 + (size_t)tap * 1572864;   // 786432 elems * 2B
      #pragma unroll
      for (int it = 0; it < 4; ++it) {
        int ofs = tid * 16 + it * 4096;
        int row = ofs >> 7, bc = swz(row, ofs & 127);
        gl16(wt + (size_t)row * 1024 + bc, (char*)&As[buf][tap][0] + ofs);
      }
    }
    #pragma unroll
    for (int it = 0; it < 4; ++it) {       // B rows 0..127
      int ofs = tid * 16 + it * 4096;
      int row = ofs >> 7, bc = swz(row, ofs & 127);
      gl16(xb0 + (size_t)row * 1024 + bc, (char*)&Bs[buf][0] + ofs);
    }
    if (tid < 16) {                        // B rows 128,129 (16 lanes x 16B = 256B)
      int row = 128 + (tid >> 3);
      int bc  = swz(row, (tid & 7) * 16);
      gl16(xb0 + (size_t)row * 1024 + bc, (char*)&Bs[buf][0] + 128 * 128 + tid * 16);
    }
  };

  STAGE(0, 0);
  int cur = 0;
  for (int k0 = 0; k0 < 512; k0 += 64) {
    __syncthreads();                       // buf[cur] ready (vmcnt drain); prev reads done
    if (k0 < 448) STAGE(k0 + 64, cur ^ 1); // in flight across the 96-MFMA block below
    #pragma unroll
    for (int tap = 0; tap < 3; ++tap) {
      const int rswA = (lr & 7) << 4;
      const int rswB = ((lr + tap) & 7) << 4;
      #pragma unroll
      for (int kk = 0; kk < 2; ++kk) {
        const int colA = (kk * 64 + lg * 16) ^ rswA;
        const int colB = (kk * 64 + lg * 16) ^ rswB;
        bf16x8 a[4], bb[4];
        #pragma unroll
        for (int i = 0; i < 4; ++i)
          a[i] = *(const bf16x8*)((const char*)&As[cur][tap][0] + (wm + i * 16 + lr) * 128 + colA);
        #pragma unroll
        for (int j = 0; j < 4; ++j)
          bb[j] = *(const bf16x8*)((const char*)&Bs[cur][0] + (wn + j * 16 + lr + tap) * 128 + colB);
        #pragma unroll
        for (int i = 0; i < 4; ++i)
          #pragma unroll
          for (int j = 0; j < 4; ++j)
            acc[i][j] = __builtin_amdgcn_mfma_f32_16x16x32_bf16(a[i], bb[j], acc[i][j], 0, 0, 0);
      }
    }
    cur ^= 1;
  }

  const int part = o0 >> 9;   // uniform per block (o-tile 128 | 512)
  #pragma unroll
  for (int i = 0; i < 4; ++i) {
    #pragma unroll
    for (int j = 0; j < 4; ++j) {
      int mbase = o0 + wm + i * 16 + lg * 4;
      int l = l0 + wn + j * 16 + lr;
      #pragma unroll
      for (int r = 0; r < 4; ++r) {
        int o = mbase + r;
        float v = acc[i][j][r] + bias[o];
        int rem = o & 511;
        int h = rem >> 6, d = rem & 63;
        size_t bh = (size_t)(b * 8 + h);
        if (part == 0)      Qb[(bh * 512 + l) * 64 + d] = f2b(v * 0.125f);
        else if (part == 1) Kb[(bh * 512 + l) * 64 + d] = f2b(v);
        else                Vt[(bh * 64 + d) * 512 + l] = f2b(v);
      }
    }
  }
}

// ---------------- flash attention fwd: out0 + (rowmax, 1/denom) ----------------
__global__ void __launch_bounds__(256) flash_fwd(
    const bf16* __restrict__ Qb, const bf16* __restrict__ Kb, const bf16* __restrict__ Vt,
    float* __restrict__ out0, float* __restrict__ m_arr, float* __restrict__ li_arr) {
  __shared__ __align__(16) bf16 Qs[64 * 64];
  __shared__ __align__(16) bf16 Ks[64 * 64];
  __shared__ __align__(16) bf16 Vs[64 * 64];
  __shared__ __align__(16) bf16 Ps[4][16 * 72];   // padded rows (144 B) vs bank conflicts
  const int tid = threadIdx.x;
  const int t0 = blockIdx.x * 64;
  const int bh = blockIdx.y;
  const int b = bh >> 3, h = bh & 7;
  const int lane = tid & 63, w = tid >> 6;
  const int lg = lane >> 4, lr = lane & 15;
  const int rsw = (lr & 7) << 4;

  #pragma unroll
  for (int it = 0; it < 2; ++it) {
    int ofs = tid * 16 + it * 4096;
    int row = ofs >> 7, bc = swz(row, ofs & 127);
    gl16((const char*)(Qb + ((size_t)bh * 512 + t0 + row) * 64) + bc, (char*)Qs + ofs);
  }

  float mreg[4] = {-1e30f, -1e30f, -1e30f, -1e30f};
  float lreg[4] = {0.f, 0.f, 0.f, 0.f};
  f32x4 oacc[4] = {};

  for (int sc = 0; sc < 8; ++sc) {
    __syncthreads();
    #pragma unroll
    for (int it = 0; it < 2; ++it) {
      int ofs = tid * 16 + it * 4096;
      int row = ofs >> 7, bc = swz(row, ofs & 127);
      gl16((const char*)(Kb + ((size_t)bh * 512 + sc * 64 + row) * 64) + bc, (char*)Ks + ofs);
      gl16((const char*)(Vt + ((size_t)bh * 64 + row) * 512 + sc * 64) + bc, (char*)Vs + ofs);
    }
    __syncthreads();

    bf16x8 aq[2];
    #pragma unroll
    for (int kk = 0; kk < 2; ++kk)
      aq[kk] = *(const bf16x8*)((const char*)Qs + (w * 16 + lr) * 128 + ((kk * 64 + lg * 16) ^ rsw));

    f32x4 s4[4] = {};
    #pragma unroll
    for (int j = 0; j < 4; ++j)
      #pragma unroll
      for (int kk = 0; kk < 2; ++kk) {
        bf16x8 bk = *(const bf16x8*)((const char*)Ks + (j * 16 + lr) * 128 + ((kk * 64 + lg * 16) ^ rsw));
        s4[j] = __builtin_amdgcn_mfma_f32_16x16x32_bf16(aq[kk], bk, s4[j], 0, 0, 0);
      }

    float cm[4], mnew[4], alpha[4], rs[4];
    #pragma unroll
    for (int r = 0; r < 4; ++r) {
      cm[r] = fmaxf(fmaxf(s4[0][r], s4[1][r]), fmaxf(s4[2][r], s4[3][r]));
      cm[r] = fmaxf(cm[r], __shfl_xor(cm[r], 1, 64));
      cm[r] = fmaxf(cm[r], __shfl_xor(cm[r], 2, 64));
      cm[r] = fmaxf(cm[r], __shfl_xor(cm[r], 4, 64));
      cm[r] = fmaxf(cm[r], __shfl_xor(cm[r], 8, 64));
      mnew[r] = fmaxf(mreg[r], cm[r]);
      alpha[r] = __expf(mreg[r] - mnew[r]);
      rs[r] = 0.f;
    }
    #pragma unroll
    for (int j = 0; j < 4; ++j)
      #pragma unroll
      for (int r = 0; r < 4; ++r) {
        float p = __expf(s4[j][r] - mnew[r]);
        s4[j][r] = p;
        rs[r] += p;
      }
    #pragma unroll
    for (int r = 0; r < 4; ++r) {
      rs[r] += __shfl_xor(rs[r], 1, 64);
      rs[r] += __shfl_xor(rs[r], 2, 64);
      rs[r] += __shfl_xor(rs[r], 4, 64);
      rs[r] += __shfl_xor(rs[r], 8, 64);
      lreg[r] = lreg[r] * alpha[r] + rs[r];
      mreg[r] = mnew[r];
    }
    #pragma unroll
    for (int j = 0; j < 4; ++j)
      #pragma unroll
      for (int r = 0; r < 4; ++r)
        oacc[j][r] *= alpha[r];

    // P -> per-wave LDS (bf16, padded rows), then read back as A-fragments
    #pragma unroll
    for (int j = 0; j < 4; ++j)
      #pragma unroll
      for (int r = 0; r < 4; ++r)
        Ps[w][(lg * 4 + r) * 72 + j * 16 + lr] = f2b(s4[j][r]);
    asm volatile("s_waitcnt lgkmcnt(0)" ::: "memory");
    __builtin_amdgcn_sched_barrier(0);

    bf16x8 pa[2];
    #pragma unroll
    for (int kk = 0; kk < 2; ++kk)
      pa[kk] = *(const bf16x8*)((const char*)&Ps[w][0] + lr * 144 + kk * 64 + lg * 16);

    #pragma unroll
    for (int j = 0; j < 4; ++j)
      #pragma unroll
      for (int kk = 0; kk < 2; ++kk) {
        bf16x8 bv = *(const bf16x8*)((const char*)Vs + (j * 16 + lr) * 128 + ((kk * 64 + lg * 16) ^ rsw));
        oacc[j] = __builtin_amdgcn_mfma_f32_16x16x32_bf16(pa[kk], bv, oacc[j], 0, 0, 0);
      }
  }

  float il[4];
  #pragma unroll
  for (int r = 0; r < 4; ++r) il[r] = 1.f / lreg[r];

  #pragma unroll
  for (int j = 0; j < 4; ++j)
    #pragma unroll
    for (int r = 0; r < 4; ++r) {
      int t = t0 + w * 16 + lg * 4 + r;
      out0[(size_t)t * 16384 + (size_t)b * 512 + h * 64 + j * 16 + lr] = oacc[j][r] * il[r];
    }
  if (lr == 0) {
    #pragma unroll
    for (int r = 0; r < 4; ++r) {
      int t = t0 + w * 16 + lg * 4 + r;
      m_arr[bh * 512 + t] = mreg[r];
      li_arr[bh * 512 + t] = il[r];
    }
  }
}

// ---------------- avg_weights: recompute P from saved (m, 1/l), sum heads ----------------
__global__ void __launch_bounds__(256) avg_attn(
    const bf16* __restrict__ Qb, const bf16* __restrict__ Kb,
    const float* __restrict__ m_arr, const float* __restrict__ li_arr,
    float* __restrict__ out1) {
  __shared__ __align__(16) bf16 Qs[64 * 64];
  __shared__ __align__(16) bf16 Ks[128 * 64];
  const int tid = threadIdx.x;
  const int s0 = blockIdx.x * 128;
  const int t0 = blockIdx.y * 64;
  const int b  = blockIdx.z;
  const int lane = tid & 63, w = tid >> 6;
  const int lg = lane >> 4, lr = lane & 15;
  const int rsw = (lr & 7) << 4;

  f32x4 avg4[8] = {};

  for (int h = 0; h < 8; ++h) {
    int bh = b * 8 + h;
    __syncthreads();
    #pragma unroll
    for (int it = 0; it < 2; ++it) {
      int ofs = tid * 16 + it * 4096;
      int row = ofs >> 7, bc = swz(row, ofs & 127);
      gl16((const char*)(Qb + ((size_t)bh * 512 + t0 + row) * 64) + bc, (char*)Qs + ofs);
    }
    #pragma unroll
    for (int it = 0; it < 4; ++it) {
      int ofs = tid * 16 + it * 4096;
      int row = ofs >> 7, bc = swz(row, ofs & 127);
      gl16((const char*)(Kb + ((size_t)bh * 512 + s0 + row) * 64) + bc, (char*)Ks + ofs);
    }
    __syncthreads();

    float mv[4], iv[4];
    #pragma unroll
    for (int r = 0; r < 4; ++r) {
      int t = t0 + w * 16 + lg * 4 + r;
      mv[r] = m_arr[bh * 512 + t];
      iv[r] = li_arr[bh * 512 + t];
    }

    bf16x8 aq[2];
    #pragma unroll
    for (int kk = 0; kk < 2; ++kk)
      aq[kk] = *(const bf16x8*)((const char*)Qs + (w * 16 + lr) * 128 + ((kk * 64 + lg * 16) ^ rsw));

    #pragma unroll
    for (int j = 0; j < 8; ++j) {
      f32x4 s4 = {};
      #pragma unroll
      for (int kk = 0; kk < 2; ++kk) {
        bf16x8 bk = *(const bf16x8*)((const char*)Ks + (j * 16 + lr) * 128 + ((kk * 64 + lg * 16) ^ rsw));
        s4 = __builtin_amdgcn_mfma_f32_16x16x32_bf16(aq[kk], bk, s4, 0, 0, 0);
      }
      #pragma unroll
      for (int r = 0; r < 4; ++r)
        avg4[j][r] += __expf(s4[r] - mv[r]) * iv[r];
    }
  }

  #pragma unroll
  for (int j = 0; j < 8; ++j)
    #pragma unroll
    for (int r = 0; r < 4; ++r) {
      int t = t0 + w * 16 + lg * 4 + r;
      out1[((size_t)b * 512 + t) * 512 + s0 + j * 16 + lr] = avg4[j][r] * 0.125f;
    }
}

extern "C" void kernel_launch(void* const* d_in, const int* in_sizes, int n_in,
                              void* d_out, int out_size, void* d_ws, size_t ws_size,
                              hipStream_t stream) {
  const float* query = (const float*)d_in[0];
  const float* wconv = (const float*)d_in[1];
  const float* bias  = (const float*)d_in[2];
  // d_in[3] (attention_weight) and d_in[4] (bpps) are unused by the reference.

  char* ws = (char*)d_ws;
  bf16* Xp  = (bf16*)(ws + 0);                 // 16,842,752 B  (32 x 514 x 512, halo rows)
  bf16* Wb  = (bf16*)(ws + 16842752);          //  4,718,592 B
  bf16* Qb  = (bf16*)(ws + 21561344);          // 16,777,216 B
  bf16* Kb  = (bf16*)(ws + 38338560);          // 16,777,216 B
  bf16* Vt  = (bf16*)(ws + 55115776);          // 16,777,216 B
  float* m_arr  = (float*)(ws + 71892992);     //    524,288 B
  float* li_arr = (float*)(ws + 72417280);     //    524,288 B

  float* out0 = (float*)d_out;                 // (512,32,512)
  float* out1 = out0 + 8388608;                // (32,512,512)

  hipMemsetAsync(Xp, 0, 16842752, stream);     // zero halo rows (interior overwritten by prep_x)
  prep_x<<<16384, 256, 0, stream>>>(query, Xp);
  prep_w<<<9216, 256, 0, stream>>>(wconv, Wb);
  conv_qkv<<<dim3(4, 12, 32), 256, 0, stream>>>(Wb, Xp, bias, Qb, Kb, Vt);
  flash_fwd<<<dim3(8, 256), 256, 0, stream>>>(Qb, Kb, Vt, out0, m_arr, li_arr);
  avg_attn<<<dim3(4, 8, 32), 256, 0, stream>>>(Qb, Kb, m_arr, li_arr, out1);
}